// Round 1
// baseline (31.426 us; speedup 1.0000x reference)
//
#include <hip/hip_runtime.h>
#include <hip/hip_bf16.h>

// MeanAggregator: out[b] = mean(features[neighbor_idx[b, :cnt[b]]]) if cnt>0
//                 else features[nodes[b]]
//
// Layout: 32 lanes per node (each lane owns one float4 = 4 of 128 feats).
// Block 256 threads = 8 nodes. Coalesced 512B row reads.

#define B_NODES 50000
#define NUM_SAMPLE 10
#define D_FEAT 128
#define VEC_PER_ROW (D_FEAT / 4)   // 32 float4 per row

__global__ __launch_bounds__(256) void mean_agg_kernel(
    const int* __restrict__ nodes,
    const int* __restrict__ neighbor_idx,
    const int* __restrict__ neighbor_count,
    const float4* __restrict__ features4,   // [N_NODES * 32]
    float4* __restrict__ out4)              // [B * 32]
{
    const int node = blockIdx.x * 8 + (threadIdx.x >> 5);
    const int lane = threadIdx.x & 31;
    if (node >= B_NODES) return;

    const int cnt = neighbor_count[node];

    if (cnt == 0) {
        // Fall back to own feature row.
        const int src = nodes[node];
        out4[node * VEC_PER_ROW + lane] = features4[src * VEC_PER_ROW + lane];
        return;
    }

    float4 acc = make_float4(0.f, 0.f, 0.f, 0.f);
    const int* nb = neighbor_idx + node * NUM_SAMPLE;
    #pragma unroll 1
    for (int s = 0; s < cnt; ++s) {
        const int idx = nb[s];
        const float4 v = features4[idx * VEC_PER_ROW + lane];
        acc.x += v.x; acc.y += v.y; acc.z += v.z; acc.w += v.w;
    }
    const float inv = 1.0f / (float)cnt;
    acc.x *= inv; acc.y *= inv; acc.z *= inv; acc.w *= inv;
    out4[node * VEC_PER_ROW + lane] = acc;
}

extern "C" void kernel_launch(void* const* d_in, const int* in_sizes, int n_in,
                              void* d_out, int out_size, void* d_ws, size_t ws_size,
                              hipStream_t stream) {
    const int*    nodes          = (const int*)d_in[0];
    const int*    neighbor_idx   = (const int*)d_in[1];
    const int*    neighbor_count = (const int*)d_in[2];
    const float4* features4      = (const float4*)d_in[3];
    float4*       out4           = (float4*)d_out;

    const int nodes_per_block = 8;            // 256 threads / 32 lanes-per-node
    const int grid = (B_NODES + nodes_per_block - 1) / nodes_per_block;
    mean_agg_kernel<<<grid, 256, 0, stream>>>(nodes, neighbor_idx, neighbor_count,
                                              features4, out4);
}

// Round 2
// 27.080 us; speedup vs baseline: 1.1605x; 1.1605x over previous
//
#include <hip/hip_runtime.h>
#include <hip/hip_bf16.h>

// MeanAggregator: out[b] = mean(features[neighbor_idx[b, :cnt[b]]]) if cnt>0
//                 else features[nodes[b]]
//
// 32 lanes per node (one float4 of the 128-float row each); block 256 = 8 nodes.
// All NUM_SAMPLE gathers are issued unconditionally with predicated addresses
// (padded slots re-read the base row -> L1 hit) so their latencies overlap,
// then a 0/1-weighted sum accumulates. cnt==0 folds in via base = nodes[b].

#define B_NODES 50000
#define NUM_SAMPLE 10
#define D_FEAT 128
#define VEC_PER_ROW (D_FEAT / 4)   // 32 float4 per row

__global__ __launch_bounds__(256) void mean_agg_kernel(
    const int* __restrict__ nodes,
    const int* __restrict__ neighbor_idx,
    const int* __restrict__ neighbor_count,
    const float4* __restrict__ features4,   // [N_NODES * 32]
    float4* __restrict__ out4)              // [B * 32]
{
    const int node = blockIdx.x * 8 + (threadIdx.x >> 5);
    const int lane = threadIdx.x & 31;
    if (node >= B_NODES) return;

    const int cnt = neighbor_count[node];
    const int own = nodes[node];

    // 10 indices as 5x int2 (node*40 bytes is always 8B-aligned).
    const int2* nb2 = (const int2*)(neighbor_idx + node * NUM_SAMPLE);
    const int2 q0 = nb2[0], q1 = nb2[1], q2 = nb2[2], q3 = nb2[3], q4 = nb2[4];
    const int idx[NUM_SAMPLE] = {q0.x, q0.y, q1.x, q1.y, q2.x, q2.y, q3.x, q3.y, q4.x, q4.y};

    // Row that padded / empty slots read (already hot in L1 after slot 0).
    const int base = (cnt == 0) ? own : idx[0];

    // Issue all gathers back-to-back: 10 independent loads in flight.
    float4 v[NUM_SAMPLE];
    #pragma unroll
    for (int s = 0; s < NUM_SAMPLE; ++s) {
        const int e = (s < cnt) ? idx[s] : base;
        v[s] = features4[e * VEC_PER_ROW + lane];
    }

    // Slot 0 always has weight 1 (it's idx[0] if cnt>0, own row if cnt==0).
    float4 acc = v[0];
    #pragma unroll
    for (int s = 1; s < NUM_SAMPLE; ++s) {
        const float w = (s < cnt) ? 1.0f : 0.0f;
        acc.x += w * v[s].x;
        acc.y += w * v[s].y;
        acc.z += w * v[s].z;
        acc.w += w * v[s].w;
    }

    const float inv = 1.0f / (float)((cnt > 1) ? cnt : 1);
    acc.x *= inv; acc.y *= inv; acc.z *= inv; acc.w *= inv;
    out4[node * VEC_PER_ROW + lane] = acc;
}

extern "C" void kernel_launch(void* const* d_in, const int* in_sizes, int n_in,
                              void* d_out, int out_size, void* d_ws, size_t ws_size,
                              hipStream_t stream) {
    const int*    nodes          = (const int*)d_in[0];
    const int*    neighbor_idx   = (const int*)d_in[1];
    const int*    neighbor_count = (const int*)d_in[2];
    const float4* features4      = (const float4*)d_in[3];
    float4*       out4           = (float4*)d_out;

    const int nodes_per_block = 8;            // 256 threads / 32 lanes-per-node
    const int grid = (B_NODES + nodes_per_block - 1) / nodes_per_block;
    mean_agg_kernel<<<grid, 256, 0, stream>>>(nodes, neighbor_idx, neighbor_count,
                                              features4, out4);
}